// Round 1
// baseline (188.845 us; speedup 1.0000x reference)
//
#include <hip/hip_runtime.h>

#define N_TOK 9216
#define C_DIM 64
#define I_DIM 32
#define BOT 16
#define B_SZ 2
#define N_TILES 144  // N_TOK / 64

typedef short bf16x8 __attribute__((ext_vector_type(8)));
typedef float f32x4 __attribute__((ext_vector_type(4)));

__device__ __forceinline__ unsigned short f2bf(float f) {
  unsigned u = __float_as_uint(f);
  u += 0x7fffu + ((u >> 16) & 1u);
  return (unsigned short)(u >> 16);
}

// ---------------- pooled = mean over spatial ----------------
__global__ __launch_bounds__(256) void pool_kernel(const float* __restrict__ x,
                                                   float* __restrict__ pooled) {
  int bc = blockIdx.x;  // b*64 + c, 0..127
  const float* p = x + (size_t)bc * N_TOK;
  float s = 0.f;
  for (int t = threadIdx.x; t < N_TOK; t += 256) s += p[t];
#pragma unroll
  for (int off = 32; off >= 1; off >>= 1) s += __shfl_down(s, off, 64);
  __shared__ float red[4];
  int wid = threadIdx.x >> 6, lane = threadIdx.x & 63;
  if (lane == 0) red[wid] = s;
  __syncthreads();
  if (threadIdx.x == 0)
    pooled[bc] = (red[0] + red[1] + red[2] + red[3]) * (1.0f / N_TOK);
}

// ---------------- gate = sigmoid(cg2(relu(cg1(pooled)))) ----------------
__global__ __launch_bounds__(128) void gate_kernel(
    const float* __restrict__ pooled, const float* __restrict__ cg1_w,
    const float* __restrict__ cg1_b, const float* __restrict__ cg2_w,
    const float* __restrict__ cg2_b, float* __restrict__ gate) {
  __shared__ float hl[B_SZ][BOT];
  int tid = threadIdx.x;
  if (tid < B_SZ * BOT) {
    int b = tid >> 4, i = tid & 15;
    float a = cg1_b[i];
    for (int c = 0; c < C_DIM; ++c)
      a += cg1_w[i * C_DIM + c] * pooled[b * C_DIM + c];
    hl[b][i] = a > 0.f ? a : 0.f;
  }
  __syncthreads();
  {
    int b = tid >> 6, c = tid & 63;
    float z = cg2_b[c];
    for (int j = 0; j < BOT; ++j) z += cg2_w[c * BOT + j] * hl[b][j];
    gate[b * C_DIM + c] = 1.f / (1.f + __expf(-z));
  }
}

// ---------------- projections: Q/K row-major [N,32] bf16, V^T [32,N] bf16 ----------------
// mat 0 -> theta (pre-scaled by 1/TEMPERATURE), 1 -> phi, 2 -> g (transposed out)
__global__ __launch_bounds__(256) void proj_kernel(
    const float* __restrict__ x, const float* __restrict__ g_w,
    const float* __restrict__ theta_w, const float* __restrict__ phi_w,
    unsigned short* __restrict__ Q, unsigned short* __restrict__ K,
    unsigned short* __restrict__ VT) {
  int mat = blockIdx.y, b = blockIdx.z;
  int n = blockIdx.x * 256 + threadIdx.x;
  __shared__ float wl[I_DIM * C_DIM];
  const float* wsrc = (mat == 0) ? theta_w : ((mat == 1) ? phi_w : g_w);
  float scale = (mat == 0) ? (1.0f / 1.5f) : 1.0f;
  for (int t = threadIdx.x; t < I_DIM * C_DIM; t += 256) wl[t] = wsrc[t] * scale;
  __syncthreads();
  float acc[I_DIM];
#pragma unroll
  for (int i = 0; i < I_DIM; ++i) acc[i] = 0.f;
  const float* xb = x + (size_t)b * C_DIM * N_TOK + n;
  for (int c = 0; c < C_DIM; ++c) {
    float xv = xb[(size_t)c * N_TOK];
#pragma unroll
    for (int i = 0; i < I_DIM; ++i) acc[i] += wl[i * C_DIM + c] * xv;
  }
  if (mat < 2) {
    unsigned short* dst = ((mat == 0) ? Q : K) + ((size_t)b * N_TOK + n) * I_DIM;
    unsigned uw[16];
#pragma unroll
    for (int k = 0; k < 16; ++k)
      uw[k] = (unsigned)f2bf(acc[2 * k]) | ((unsigned)f2bf(acc[2 * k + 1]) << 16);
    uint4* d4 = (uint4*)dst;
#pragma unroll
    for (int k = 0; k < 4; ++k)
      d4[k] = make_uint4(uw[4 * k], uw[4 * k + 1], uw[4 * k + 2], uw[4 * k + 3]);
  } else {
#pragma unroll
    for (int i = 0; i < I_DIM; ++i)
      VT[((size_t)b * I_DIM + i) * N_TOK + n] = f2bf(acc[i]);
  }
}

// ---------------- flash attention (no-max softmax), 1 wave = 32 Q rows ----------------
// Q,K: [B][N][32] bf16 (Q pre-scaled by 1/T). VT: [B][32][N] bf16.
// Ypart: [KS][B][N][32] f32 unnormalized. Lpart: [KS][B][N] f32 rowsums.
__global__ __launch_bounds__(64, 4) void attn_kernel(
    const unsigned short* __restrict__ Q, const unsigned short* __restrict__ Kg,
    const unsigned short* __restrict__ VT, float* __restrict__ Ypart,
    float* __restrict__ Lpart, int tps) {
  const int lane = threadIdx.x;
  const int m = lane & 15, quad = lane >> 4;
  const int qw = blockIdx.x, ks = blockIdx.y, b = blockIdx.z;
  const int q0 = qw * 32;
  const unsigned short* Qb = Q + (size_t)b * N_TOK * I_DIM;
  const unsigned short* Kb = Kg + (size_t)b * N_TOK * I_DIM;
  const unsigned short* Vb = VT + (size_t)b * I_DIM * N_TOK;

  const f32x4 vzero = {0.f, 0.f, 0.f, 0.f};

  // Q A-fragments for the two 16-row subtiles (held across the whole K loop)
  bf16x8 aq0 = *(const bf16x8*)(Qb + (size_t)(q0 + m) * I_DIM + quad * 8);
  bf16x8 aq1 = *(const bf16x8*)(Qb + (size_t)(q0 + 16 + m) * I_DIM + quad * 8);

  f32x4 accy[2][2];  // [msub][ntile of V cols]
  f32x4 accl[2];     // rowsum accumulators (col 0 holds the sums)
#pragma unroll
  for (int a = 0; a < 2; ++a) {
    accl[a] = vzero;
#pragma unroll
    for (int t = 0; t < 2; ++t) accy[a][t] = vzero;
  }

  bf16x8 bones;  // B-fragment: ones in column n==0 -> D[:,0] = rowsum(A)
  {
    short o = (m == 0) ? (short)0x3F80 : (short)0;  // bf16(1.0)
#pragma unroll
    for (int j = 0; j < 8; ++j) bones[j] = o;
  }

  __shared__ __align__(16) unsigned short Plds[2][16][72];  // per-wave P scratch

  const int kt0 = ks * tps;
  for (int kt = kt0; kt < kt0 + tps; ++kt) {
    const int k0 = kt * 64;
    // ---- S = Q @ K^T (pre-scaled) ----
    f32x4 s0[4], s1[4];
    const unsigned short* kp = Kb + (size_t)(k0 + m) * I_DIM + quad * 8;
#pragma unroll
    for (int nsub = 0; nsub < 4; ++nsub) {
      bf16x8 bk = *(const bf16x8*)(kp + nsub * 16 * I_DIM);
      s0[nsub] = __builtin_amdgcn_mfma_f32_16x16x32_bf16(aq0, bk, vzero, 0, 0, 0);
      s1[nsub] = __builtin_amdgcn_mfma_f32_16x16x32_bf16(aq1, bk, vzero, 0, 0, 0);
    }
    // ---- V B-fragments (independent of P: issue early to hide latency) ----
    const unsigned short* vp = Vb + (size_t)m * N_TOK + k0 + quad * 8;
    bf16x8 bv00 = *(const bf16x8*)(vp);
    bf16x8 bv01 = *(const bf16x8*)(vp + 32);
    bf16x8 bv10 = *(const bf16x8*)(vp + (size_t)16 * N_TOK);
    bf16x8 bv11 = *(const bf16x8*)(vp + (size_t)16 * N_TOK + 32);
    // ---- P = exp(S), write to LDS (C-layout -> row-major [m][kv]) ----
#pragma unroll
    for (int nsub = 0; nsub < 4; ++nsub) {
#pragma unroll
      for (int r = 0; r < 4; ++r) {
        Plds[0][quad * 4 + r][nsub * 16 + m] = f2bf(__expf(s0[nsub][r]));
        Plds[1][quad * 4 + r][nsub * 16 + m] = f2bf(__expf(s1[nsub][r]));
      }
    }
    __syncthreads();
    // ---- read P as A-fragments; Y += P@V ; l += rowsum(P) ----
#pragma unroll
    for (int msub = 0; msub < 2; ++msub) {
      bf16x8 ap0 = *(const bf16x8*)&Plds[msub][m][quad * 8];
      bf16x8 ap1 = *(const bf16x8*)&Plds[msub][m][32 + quad * 8];
      accl[msub] = __builtin_amdgcn_mfma_f32_16x16x32_bf16(ap0, bones, accl[msub], 0, 0, 0);
      accl[msub] = __builtin_amdgcn_mfma_f32_16x16x32_bf16(ap1, bones, accl[msub], 0, 0, 0);
      f32x4 t0 = __builtin_amdgcn_mfma_f32_16x16x32_bf16(ap0, bv00, accy[msub][0], 0, 0, 0);
      accy[msub][0] = __builtin_amdgcn_mfma_f32_16x16x32_bf16(ap1, bv01, t0, 0, 0, 0);
      f32x4 t1 = __builtin_amdgcn_mfma_f32_16x16x32_bf16(ap0, bv10, accy[msub][1], 0, 0, 0);
      accy[msub][1] = __builtin_amdgcn_mfma_f32_16x16x32_bf16(ap1, bv11, t1, 0, 0, 0);
    }
    __syncthreads();
  }

  // ---- write partials ----
  const size_t base = (size_t)(ks * B_SZ + b) * N_TOK;
#pragma unroll
  for (int msub = 0; msub < 2; ++msub) {
#pragma unroll
    for (int r = 0; r < 4; ++r) {
      int row = q0 + msub * 16 + quad * 4 + r;
      float* yp = Ypart + (base + row) * I_DIM;
      yp[m] = accy[msub][0][r];
      yp[16 + m] = accy[msub][1][r];
      if (m == 0) Lpart[base + row] = accl[msub][r];
    }
  }
}

// ---------------- epilogue: y = (sum Ypart)/(sum Lpart); out = x + 0.8*gate*(W_w @ y) ----------------
__global__ __launch_bounds__(256) void epilogue_kernel(
    const float* __restrict__ x, const float* __restrict__ W_w,
    const float* __restrict__ gate, const float* __restrict__ Ypart,
    const float* __restrict__ Lpart, float* __restrict__ out, int KS) {
  __shared__ float Wl[C_DIM * I_DIM];
  __shared__ float gl[C_DIM];
  int tid = threadIdx.x;
  int b = blockIdx.y;
  int n = blockIdx.x * 256 + tid;
  for (int t = tid; t < C_DIM * I_DIM; t += 256) Wl[t] = W_w[t];
  if (tid < C_DIM) gl[tid] = gate[b * C_DIM + tid];
  __syncthreads();

  float y[I_DIM];
#pragma unroll
  for (int i = 0; i < I_DIM; ++i) y[i] = 0.f;
  float l = 0.f;
  for (int ks = 0; ks < KS; ++ks) {
    const float4* Yp =
        (const float4*)(Ypart + ((size_t)(ks * B_SZ + b) * N_TOK + n) * I_DIM);
#pragma unroll
    for (int k = 0; k < 8; ++k) {
      float4 v = Yp[k];
      y[4 * k + 0] += v.x;
      y[4 * k + 1] += v.y;
      y[4 * k + 2] += v.z;
      y[4 * k + 3] += v.w;
    }
    l += Lpart[(size_t)(ks * B_SZ + b) * N_TOK + n];
  }
  float inv = 1.f / l;
#pragma unroll
  for (int i = 0; i < I_DIM; ++i) y[i] *= inv;

  for (int c = 0; c < C_DIM; ++c) {
    float sacc = 0.f;
#pragma unroll
    for (int i = 0; i < I_DIM; ++i) sacc += Wl[c * I_DIM + i] * y[i];
    size_t idx = ((size_t)b * C_DIM + c) * N_TOK + n;
    out[idx] = x[idx] + 0.8f * gl[c] * sacc;
  }
}

extern "C" void kernel_launch(void* const* d_in, const int* in_sizes, int n_in,
                              void* d_out, int out_size, void* d_ws, size_t ws_size,
                              hipStream_t stream) {
  const float* x = (const float*)d_in[0];
  const float* g_w = (const float*)d_in[1];
  const float* theta_w = (const float*)d_in[2];
  const float* phi_w = (const float*)d_in[3];
  const float* W_w = (const float*)d_in[4];
  const float* cg1_w = (const float*)d_in[5];
  const float* cg1_b = (const float*)d_in[6];
  const float* cg2_w = (const float*)d_in[7];
  const float* cg2_b = (const float*)d_in[8];
  float* out = (float*)d_out;

  char* w = (char*)d_ws;
  const size_t bfsz = (size_t)B_SZ * N_TOK * I_DIM * sizeof(unsigned short);  // 1,179,648
  unsigned short* Qb = (unsigned short*)(w);
  unsigned short* Kb = (unsigned short*)(w + bfsz);
  unsigned short* VT = (unsigned short*)(w + 2 * bfsz);
  float* pooled = (float*)(w + 3 * bfsz);
  float* gate = pooled + B_SZ * C_DIM;
  char* w2 = w + 3 * bfsz + 1024;

  int KS = 8;  // k-split factor; shrink if workspace is small (deterministic per session)
  {
    const size_t per = (size_t)B_SZ * N_TOK * sizeof(float) * (I_DIM + 1);
    while (KS > 1 && (3 * bfsz + 1024 + (size_t)KS * per) > ws_size) KS >>= 1;
  }
  float* Lpart = (float*)w2;
  float* Ypart = (float*)(w2 + (size_t)KS * B_SZ * N_TOK * sizeof(float));
  int tps = N_TILES / KS;

  proj_kernel<<<dim3(N_TOK / 256, 3, B_SZ), 256, 0, stream>>>(x, g_w, theta_w,
                                                              phi_w, Qb, Kb, VT);
  pool_kernel<<<dim3(B_SZ * C_DIM), 256, 0, stream>>>(x, pooled);
  gate_kernel<<<dim3(1), 128, 0, stream>>>(pooled, cg1_w, cg1_b, cg2_w, cg2_b, gate);
  attn_kernel<<<dim3(N_TOK / 32, KS, B_SZ), 64, 0, stream>>>(Qb, Kb, VT, Ypart,
                                                             Lpart, tps);
  epilogue_kernel<<<dim3(N_TOK / 256, B_SZ), 256, 0, stream>>>(x, W_w, gate,
                                                               Ypart, Lpart, out, KS);
}